// Round 2
// baseline (2257.045 us; speedup 1.0000x reference)
//
#include <hip/hip_runtime.h>
#include <cstddef>

#define EPSV 0.001f

static inline int idiv(int a, int b){ return (a + b - 1) / b; }
static inline int imin(int a, int b){ return a < b ? a : b; }

// ---------------------------------------------------------------------------
// Weight repack: w (CO,CI,kz,ky,kx) -> wp[(tap*CI+ci)*CO + co]
// so that per-(tap,ci) the CO weights are contiguous and wave-uniform.
// ---------------------------------------------------------------------------
struct WPtrs { const float* w[9]; };

__global__ __launch_bounds__(256)
void repack_w(WPtrs ws, float* __restrict__ wp) {
  constexpr int off[10] = {0,6912,13824,27648,55296,110592,221184,331776,442368,454656};
  constexpr int COs[9] = {16,16,32,32,64,64,64,64,64};
  constexpr int CIs[9] = {16,16,16,32,32,64,64,64,64};
  constexpr int NTs[9] = {27,27,27,27,27,27,27,27,3};
  int idx = blockIdx.x * blockDim.x + threadIdx.x;
  if (idx >= off[9]) return;
  int L = 0;
  #pragma unroll
  for (int k = 0; k < 9; k++) if (idx >= off[k+1]) L = k + 1;
  int r  = idx - off[L];
  int CO = COs[L], CI = CIs[L], NT = NTs[L];
  int co = r % CO; int t = r / CO; int ci = t % CI; int tap = t / CI;
  wp[idx] = ws.w[L][(co*CI + ci)*NT + tap];
}

// ---------------------------------------------------------------------------
// Scatter voxel indices into dense grid (D=40,H=200,W=200), grid preset to -1.
// ---------------------------------------------------------------------------
__global__ __launch_bounds__(256)
void scatter_grid(const int* __restrict__ coors, int* __restrict__ grid, int n) {
  int i = blockIdx.x * blockDim.x + threadIdx.x;
  if (i >= n) return;
  int z = coors[4*i+1], y = coors[4*i+2], x = coors[4*i+3];
  grid[(z*200 + y)*200 + x] = i;
}

// ---------------------------------------------------------------------------
// Sparse submanifold 3x3x3 conv, 16->16, over active voxel list.
// ---------------------------------------------------------------------------
__global__ __launch_bounds__(256)
void subm16(const float* __restrict__ fin, float* __restrict__ fout,
            const int* __restrict__ coors, const int* __restrict__ grid,
            const float* __restrict__ wp, int n) {
  int i = blockIdx.x * blockDim.x + threadIdx.x;
  if (i >= n) return;
  int z = coors[4*i+1], y = coors[4*i+2], x = coors[4*i+3];
  float acc[16];
  #pragma unroll
  for (int c = 0; c < 16; c++) acc[c] = 0.f;
  for (int kz = 0; kz < 3; kz++) {
    int iz = z + kz - 1; if ((unsigned)iz >= 40u) continue;
    for (int ky = 0; ky < 3; ky++) {
      int iy = y + ky - 1; if ((unsigned)iy >= 200u) continue;
      for (int kx = 0; kx < 3; kx++) {
        int ix = x + kx - 1; if ((unsigned)ix >= 200u) continue;
        int j = grid[(iz*200 + iy)*200 + ix];
        if (j < 0) continue;
        int tap = (kz*3 + ky)*3 + kx;
        const float* fj = fin + (size_t)j*16;
        const float* wb = wp + tap*16*16;
        #pragma unroll
        for (int ci = 0; ci < 16; ci++) {
          float v = fj[ci];
          #pragma unroll
          for (int c = 0; c < 16; c++) acc[c] += v * wb[ci*16 + c];
        }
      }
    }
  }
  float* o = fout + (size_t)i*16;
  #pragma unroll
  for (int c = 0; c < 16; c++) o[c] = acc[c];
}

// ---------------------------------------------------------------------------
// L2: strided (2,2,2) pad(1,1,1) 3x3x3 conv 16->32, sparse input -> dense
// channels-last output (20,100,100,32) + new mask.
// ---------------------------------------------------------------------------
__global__ __launch_bounds__(256)
void down16to32(const float* __restrict__ fin, const int* __restrict__ grid,
                float* __restrict__ out, unsigned char* __restrict__ mout,
                const float* __restrict__ wp) {
  constexpr int OD = 20, OH = 100, OW = 100;
  int vox = blockIdx.x * blockDim.x + threadIdx.x;
  if (vox >= OD*OH*OW) return;
  int ox = vox % OW; int t = vox / OW; int oy = t % OH; int oz = t / OH;
  float acc[32];
  #pragma unroll
  for (int c = 0; c < 32; c++) acc[c] = 0.f;
  bool any = false;
  for (int kz = 0; kz < 3; kz++) {
    int iz = oz*2 - 1 + kz; if ((unsigned)iz >= 40u) continue;
    for (int ky = 0; ky < 3; ky++) {
      int iy = oy*2 - 1 + ky; if ((unsigned)iy >= 200u) continue;
      for (int kx = 0; kx < 3; kx++) {
        int ix = ox*2 - 1 + kx; if ((unsigned)ix >= 200u) continue;
        int j = grid[(iz*200 + iy)*200 + ix];
        if (j < 0) continue;
        any = true;
        int tap = (kz*3 + ky)*3 + kx;
        const float* fj = fin + (size_t)j*16;
        const float* wb = wp + (size_t)tap*16*32;
        #pragma unroll
        for (int ci = 0; ci < 16; ci++) {
          float v = fj[ci];
          #pragma unroll
          for (int c = 0; c < 32; c++) acc[c] += v * wb[ci*32 + c];
        }
      }
    }
  }
  float* o = out + (size_t)vox*32;
  #pragma unroll
  for (int c = 0; c < 32; c++) o[c] = acc[c];
  mout[vox] = any ? 1 : 0;
}

// ---------------------------------------------------------------------------
// Dense direct conv, channels-last. One thread = one output voxel x COPT
// output channels (blockIdx.y selects the channel group). Weights repacked
// [tap][ci][co] -> wave-uniform contiguous loads.
// ---------------------------------------------------------------------------
template<int ID,int IH,int IW,int OD,int OH,int OW,int CI,int CO,int COPT,
         int KD,int KH,int KW,int SD,int SH,int SW,int PD,int PH,int PW,int DOWN>
__global__ __launch_bounds__(256)
void convd(const float* __restrict__ in, float* __restrict__ out,
           const unsigned char* __restrict__ min_, unsigned char* __restrict__ mout,
           const float* __restrict__ wp) {
  constexpr int NVOX = OD*OH*OW;
  int vox = blockIdx.x * blockDim.x + threadIdx.x;
  int cog = blockIdx.y;
  if (vox >= NVOX) return;
  int ox = vox % OW; int t = vox / OW; int oy = t % OH; int oz = t / OH;
  float acc[COPT];
  #pragma unroll
  for (int c = 0; c < COPT; c++) acc[c] = 0.f;
  bool any = false;
  #pragma unroll 1
  for (int kz = 0; kz < KD; kz++) {
    int iz = oz*SD - PD + kz;
    bool bz = (unsigned)iz < (unsigned)ID;
    #pragma unroll 1
    for (int ky = 0; ky < KH; ky++) {
      int iy = oy*SH - PH + ky;
      bool by = bz && ((unsigned)iy < (unsigned)IH);
      #pragma unroll 1
      for (int kx = 0; kx < KW; kx++) {
        int ix = ox*SW - PW + kx;
        bool ok = by && ((unsigned)ix < (unsigned)IW);
        int izc = min(max(iz,0),ID-1), iyc = min(max(iy,0),IH-1), ixc = min(max(ix,0),IW-1);
        int ipos = (izc*IH + iyc)*IW + ixc;
        if constexpr (DOWN) { any = any || (ok && (min_[ipos] != 0)); }
        const float* p = in + (size_t)ipos*CI;
        int tap = (kz*KH + ky)*KW + kx;
        const float* wb = wp + ((size_t)tap*CI)*CO + cog*COPT;
        #pragma unroll 4
        for (int ci = 0; ci < CI; ci++) {
          float v = ok ? p[ci] : 0.f;
          #pragma unroll
          for (int c = 0; c < COPT; c++) acc[c] += v * wb[ci*CO + c];
        }
      }
    }
  }
  float* o = out + (size_t)vox*CO + cog*COPT;
  #pragma unroll
  for (int c = 0; c < COPT; c++) o[c] = acc[c];
  if constexpr (DOWN) { if (cog == 0) mout[vox] = any ? 1 : 0; }
}

// ---------------------------------------------------------------------------
// Masked BN stats: per-channel sum, sumsq, count -> stats[3 sections].
// block = (CO, YD). m == nullptr means "all active" (sparse layers).
// ---------------------------------------------------------------------------
template<int CO, int YD>
__global__ void bn_stats(const float* __restrict__ x, const unsigned char* __restrict__ m,
                         float* __restrict__ stats, int nvox) {
  int c  = threadIdx.x;
  int ty = threadIdx.y;
  float s = 0.f, q = 0.f, cnt = 0.f;
  for (int vox = blockIdx.x*YD + ty; vox < nvox; vox += gridDim.x*YD) {
    bool act = m ? (m[vox] != 0) : true;
    if (act) {
      float v = x[(size_t)vox*CO + c];
      s += v; q += v*v; cnt += 1.f;
    }
  }
  __shared__ float ls[YD][CO];
  __shared__ float lq[YD][CO];
  __shared__ float lc[YD];
  ls[ty][c] = s; lq[ty][c] = q;
  if (c == 0) lc[ty] = cnt;
  __syncthreads();
  if (ty == 0) {
    #pragma unroll
    for (int i = 1; i < YD; i++) { s += ls[i][c]; q += lq[i][c]; }
    atomicAdd(&stats[c], s);
    atomicAdd(&stats[CO + c], q);
    if (c == 0) {
      float tc = 0.f;
      #pragma unroll
      for (int i = 0; i < YD; i++) tc += lc[i];
      atomicAdd(&stats[2*CO], tc);
    }
  }
}

// ---------------------------------------------------------------------------
// BN normalize + ReLU + mask, in place.
// ---------------------------------------------------------------------------
template<int CO>
__global__ __launch_bounds__(256)
void bn_apply(float* __restrict__ x, const unsigned char* __restrict__ m,
              const float* __restrict__ stats, const float* __restrict__ g,
              const float* __restrict__ b, int nvox) {
  int idx = blockIdx.x * blockDim.x + threadIdx.x;
  int vox = idx / CO, c = idx % CO;
  if (vox >= nvox) return;
  float cnt   = fmaxf(stats[2*CO], 1.f);
  float mean  = stats[c] / cnt;
  float var   = stats[CO + c] / cnt - mean*mean;
  float scale = g[c] * rsqrtf(var + EPSV);
  float v = (x[idx] - mean) * scale + b[c];
  v = fmaxf(v, 0.f);
  bool act = m ? (m[vox] != 0) : true;
  x[idx] = act ? v : 0.f;
}

// ---------------------------------------------------------------------------
// Final layout: x8 (5,25,11,64) channels-last -> out (1, 64*11, 5, 25).
// ---------------------------------------------------------------------------
__global__ __launch_bounds__(256)
void write_out(const float* __restrict__ x, float* __restrict__ out) {
  int idx = blockIdx.x * blockDim.x + threadIdx.x;
  if (idx >= 64*11*5*25) return;
  int y = idx % 25; int t = idx / 25;
  int z = t % 5;  t /= 5;
  int wx = t % 11; int c = t / 11;
  out[idx] = x[(((z*25 + y)*11) + wx)*64 + c];
}

// ---------------------------------------------------------------------------
extern "C" void kernel_launch(void* const* d_in, const int* in_sizes, int n_in,
                              void* d_out, int out_size, void* d_ws, size_t ws_size,
                              hipStream_t stream) {
  const float* vf    = (const float*)d_in[0];
  const int*   coors = (const int*)d_in[1];
  int n = in_sizes[0] / 16;

  // setup_inputs() dict order is INTERLEAVED: vf, coors, batch_size,
  // input_shape, then (w0,g0,b0), (w1,g1,b1), ... (w8,g8,b8).
  const float *w[9], *g[9], *b[9];
  for (int i = 0; i < 9; i++) {
    w[i] = (const float*)d_in[4 + 3*i];
    g[i] = (const float*)d_in[5 + 3*i];
    b[i] = (const float*)d_in[6 + 3*i];
  }
  float* out = (float*)d_out;

  // ---- workspace bump allocator ----
  char* wsb = (char*)d_ws;
  size_t off = 0;
  auto alloc = [&](size_t bytes) -> void* {
    void* p = wsb + off;
    off += (bytes + 255) & ~(size_t)255;
    return p;
  };
  int*   grid0 = (int*)  alloc((size_t)40*200*200*4);
  float* wp    = (float*)alloc((size_t)454656*4);
  float* fA    = (float*)alloc((size_t)n*16*4);
  float* fB    = (float*)alloc((size_t)n*16*4);
  float* dA    = (float*)alloc((size_t)20*100*100*32*4);
  float* dB    = (float*)alloc((size_t)20*100*100*32*4);
  unsigned char* m2 = (unsigned char*)alloc(20*100*100);
  unsigned char* m4 = (unsigned char*)alloc(10*50*50);
  unsigned char* m6 = (unsigned char*)alloc(5*25*24);
  unsigned char* m8 = (unsigned char*)alloc(5*25*11);
  float* stats = (float*)alloc((size_t)9*160*4);

  float* st[9];
  for (int i = 0; i < 9; i++) st[i] = stats + i*160;

  hipMemsetAsync(grid0, 0xFF, (size_t)40*200*200*4, stream);
  hipMemsetAsync(stats, 0, (size_t)9*160*4, stream);

  WPtrs wps; for (int i = 0; i < 9; i++) wps.w[i] = w[i];
  repack_w<<<idiv(454656,256), 256, 0, stream>>>(wps, wp);
  scatter_grid<<<idiv(n,256), 256, 0, stream>>>(coors, grid0, n);

  // offsets into wp (floats)
  const int WO0=0, WO1=6912, WO2=13824, WO3=27648, WO4=55296,
            WO5=110592, WO6=221184, WO7=331776, WO8=442368;

  // ---- L0, L1: sparse subm 16->16 ----
  subm16<<<idiv(n,256), 256, 0, stream>>>(vf, fA, coors, grid0, wp + WO0, n);
  bn_stats<16,16><<<imin(256, idiv(n,16)), dim3(16,16), 0, stream>>>(fA, nullptr, st[0], n);
  bn_apply<16><<<idiv(n*16,256), 256, 0, stream>>>(fA, nullptr, st[0], g[0], b[0], n);

  subm16<<<idiv(n,256), 256, 0, stream>>>(fA, fB, coors, grid0, wp + WO1, n);
  bn_stats<16,16><<<imin(256, idiv(n,16)), dim3(16,16), 0, stream>>>(fB, nullptr, st[1], n);
  bn_apply<16><<<idiv(n*16,256), 256, 0, stream>>>(fB, nullptr, st[1], g[1], b[1], n);

  // ---- L2: down 16->32, sparse -> dense (20,100,100) ----
  down16to32<<<idiv(200000,256), 256, 0, stream>>>(fB, grid0, dA, m2, wp + WO2);
  bn_stats<32,8><<<imin(256, idiv(200000,8)), dim3(32,8), 0, stream>>>(dA, m2, st[2], 200000);
  bn_apply<32><<<idiv(200000*32,256), 256, 0, stream>>>(dA, m2, st[2], g[2], b[2], 200000);

  // ---- L3: subm 32->32 dense ----
  convd<20,100,100, 20,100,100, 32,32,32, 3,3,3, 1,1,1, 1,1,1, 0>
      <<<dim3(idiv(200000,256),1), 256, 0, stream>>>(dA, dB, nullptr, nullptr, wp + WO3);
  bn_stats<32,8><<<imin(256, idiv(200000,8)), dim3(32,8), 0, stream>>>(dB, m2, st[3], 200000);
  bn_apply<32><<<idiv(200000*32,256), 256, 0, stream>>>(dB, m2, st[3], g[3], b[3], 200000);

  // ---- L4: down 32->64 -> (10,50,50) ----
  convd<20,100,100, 10,50,50, 32,64,32, 3,3,3, 2,2,2, 1,1,1, 1>
      <<<dim3(idiv(25000,256),2), 256, 0, stream>>>(dB, dA, m2, m4, wp + WO4);
  bn_stats<64,4><<<imin(256, idiv(25000,4)), dim3(64,4), 0, stream>>>(dA, m4, st[4], 25000);
  bn_apply<64><<<idiv(25000*64,256), 256, 0, stream>>>(dA, m4, st[4], g[4], b[4], 25000);

  // ---- L5: subm 64->64 ----
  convd<10,50,50, 10,50,50, 64,64,16, 3,3,3, 1,1,1, 1,1,1, 0>
      <<<dim3(idiv(25000,256),4), 256, 0, stream>>>(dA, dB, nullptr, nullptr, wp + WO5);
  bn_stats<64,4><<<imin(256, idiv(25000,4)), dim3(64,4), 0, stream>>>(dB, m4, st[5], 25000);
  bn_apply<64><<<idiv(25000*64,256), 256, 0, stream>>>(dB, m4, st[5], g[5], b[5], 25000);

  // ---- L6: down 64->64, stride(2,2,2) pad(1,1,0) -> (5,25,24) ----
  convd<10,50,50, 5,25,24, 64,64,16, 3,3,3, 2,2,2, 1,1,0, 1>
      <<<dim3(idiv(3000,256),4), 256, 0, stream>>>(dB, dA, m4, m6, wp + WO6);
  bn_stats<64,4><<<imin(256, idiv(3000,4)), dim3(64,4), 0, stream>>>(dA, m6, st[6], 3000);
  bn_apply<64><<<idiv(3000*64,256), 256, 0, stream>>>(dA, m6, st[6], g[6], b[6], 3000);

  // ---- L7: subm 64->64 ----
  convd<5,25,24, 5,25,24, 64,64,16, 3,3,3, 1,1,1, 1,1,1, 0>
      <<<dim3(idiv(3000,256),4), 256, 0, stream>>>(dA, dB, nullptr, nullptr, wp + WO7);
  bn_stats<64,4><<<imin(256, idiv(3000,4)), dim3(64,4), 0, stream>>>(dB, m6, st[7], 3000);
  bn_apply<64><<<idiv(3000*64,256), 256, 0, stream>>>(dB, m6, st[7], g[7], b[7], 3000);

  // ---- L8: down 64->64, k(1,1,3) s(1,1,2) p(0,0,0) -> (5,25,11) ----
  convd<5,25,24, 5,25,11, 64,64,16, 1,1,3, 1,1,2, 0,0,0, 1>
      <<<dim3(idiv(1375,256),4), 256, 0, stream>>>(dB, dA, m6, m8, wp + WO8);
  bn_stats<64,4><<<imin(256, idiv(1375,4)), dim3(64,4), 0, stream>>>(dA, m8, st[8], 1375);
  bn_apply<64><<<idiv(1375*64,256), 256, 0, stream>>>(dA, m8, st[8], g[8], b[8], 1375);

  // ---- final transpose/reshape ----
  write_out<<<idiv(88000,256), 256, 0, stream>>>(dA, out);
}

// Round 3
// 1677.934 us; speedup vs baseline: 1.3451x; 1.3451x over previous
//
#include <hip/hip_runtime.h>
#include <cstddef>

#define EPSV 0.001f

static inline int idiv(int a, int b){ return (a + b - 1) / b; }
static inline int imin(int a, int b){ return a < b ? a : b; }

// ---------------------------------------------------------------------------
// Weight repack: w (CO,CI,kz,ky,kx) -> wp[(tap*CI+ci)*CO + co]
// ---------------------------------------------------------------------------
struct WPtrs { const float* w[9]; };

__global__ __launch_bounds__(256)
void repack_w(WPtrs ws, float* __restrict__ wp) {
  constexpr int off[10] = {0,6912,13824,27648,55296,110592,221184,331776,442368,454656};
  constexpr int COs[9] = {16,16,32,32,64,64,64,64,64};
  constexpr int CIs[9] = {16,16,16,32,32,64,64,64,64};
  constexpr int NTs[9] = {27,27,27,27,27,27,27,27,3};
  int idx = blockIdx.x * blockDim.x + threadIdx.x;
  if (idx >= off[9]) return;
  int L = 0;
  #pragma unroll
  for (int k = 0; k < 9; k++) if (idx >= off[k+1]) L = k + 1;
  int r  = idx - off[L];
  int CO = COs[L], CI = CIs[L], NT = NTs[L];
  int co = r % CO; int t = r / CO; int ci = t % CI; int tap = t / CI;
  wp[idx] = ws.w[L][(co*CI + ci)*NT + tap];
}

// ---------------------------------------------------------------------------
__global__ __launch_bounds__(256)
void scatter_grid(const int* __restrict__ coors, int* __restrict__ grid, int n) {
  int i = blockIdx.x * blockDim.x + threadIdx.x;
  if (i >= n) return;
  int z = coors[4*i+1], y = coors[4*i+2], x = coors[4*i+3];
  grid[(z*200 + y)*200 + x] = i;
}

// ---------------------------------------------------------------------------
// Sparse submanifold 3x3x3 conv, 16->16, over active voxel list.
// ---------------------------------------------------------------------------
__global__ __launch_bounds__(256)
void subm16(const float* __restrict__ fin, float* __restrict__ fout,
            const int* __restrict__ coors, const int* __restrict__ grid,
            const float* __restrict__ wp, int n) {
  int i = blockIdx.x * blockDim.x + threadIdx.x;
  if (i >= n) return;
  int z = coors[4*i+1], y = coors[4*i+2], x = coors[4*i+3];
  float acc[16];
  #pragma unroll
  for (int c = 0; c < 16; c++) acc[c] = 0.f;
  for (int kz = 0; kz < 3; kz++) {
    int iz = z + kz - 1; if ((unsigned)iz >= 40u) continue;
    for (int ky = 0; ky < 3; ky++) {
      int iy = y + ky - 1; if ((unsigned)iy >= 200u) continue;
      for (int kx = 0; kx < 3; kx++) {
        int ix = x + kx - 1; if ((unsigned)ix >= 200u) continue;
        int j = grid[(iz*200 + iy)*200 + ix];
        if (j < 0) continue;
        int tap = (kz*3 + ky)*3 + kx;
        const float* fj = fin + (size_t)j*16;
        const float* wb = wp + tap*16*16;
        #pragma unroll
        for (int cq = 0; cq < 4; cq++) {
          float4 av = *reinterpret_cast<const float4*>(fj + cq*4);
          float aj[4] = {av.x, av.y, av.z, av.w};
          #pragma unroll
          for (int j4 = 0; j4 < 4; j4++) {
            #pragma unroll
            for (int c = 0; c < 16; c++) acc[c] += aj[j4] * wb[(cq*4+j4)*16 + c];
          }
        }
      }
    }
  }
  float* o = fout + (size_t)i*16;
  #pragma unroll
  for (int c = 0; c < 16; c++) o[c] = acc[c];
}

// ---------------------------------------------------------------------------
// L2: strided (2,2,2) pad(1,1,1) 3x3x3 conv 16->32, sparse -> dense
// channels-last (20,100,100,32) + new mask. COPT=16, grid.y=2.
// ---------------------------------------------------------------------------
__global__ __launch_bounds__(256)
void down16to32(const float* __restrict__ fin, const int* __restrict__ grid,
                float* __restrict__ out, unsigned char* __restrict__ mout,
                const float* __restrict__ wp) {
  constexpr int OD = 20, OH = 100, OW = 100, COPT = 16;
  int vox = blockIdx.x * blockDim.x + threadIdx.x;
  int cog = blockIdx.y;
  if (vox >= OD*OH*OW) return;
  int ox = vox % OW; int t = vox / OW; int oy = t % OH; int oz = t / OH;
  float acc[COPT];
  #pragma unroll
  for (int c = 0; c < COPT; c++) acc[c] = 0.f;
  bool any = false;
  for (int kz = 0; kz < 3; kz++) {
    int iz = oz*2 - 1 + kz; if ((unsigned)iz >= 40u) continue;
    for (int ky = 0; ky < 3; ky++) {
      int iy = oy*2 - 1 + ky; if ((unsigned)iy >= 200u) continue;
      for (int kx = 0; kx < 3; kx++) {
        int ix = ox*2 - 1 + kx; if ((unsigned)ix >= 200u) continue;
        int j = grid[(iz*200 + iy)*200 + ix];
        if (j < 0) continue;
        any = true;
        int tap = (kz*3 + ky)*3 + kx;
        const float* fj = fin + (size_t)j*16;
        const float* wb = wp + (size_t)tap*16*32 + cog*COPT;
        #pragma unroll
        for (int cq = 0; cq < 4; cq++) {
          float4 av = *reinterpret_cast<const float4*>(fj + cq*4);
          float aj[4] = {av.x, av.y, av.z, av.w};
          #pragma unroll
          for (int j4 = 0; j4 < 4; j4++) {
            #pragma unroll
            for (int c = 0; c < COPT; c++) acc[c] += aj[j4] * wb[(cq*4+j4)*32 + c];
          }
        }
      }
    }
  }
  float* o = out + (size_t)vox*32 + cog*COPT;
  #pragma unroll
  for (int c = 0; c < COPT; c++) o[c] = acc[c];
  if (cog == 0) mout[vox] = any ? 1 : 0;
}

// ---------------------------------------------------------------------------
// Dense direct conv, channels-last, register tile VPT voxels x COPT channels.
// Voxels interleaved at +NTH so lane->address stays coalesced (stride CI).
// Weights [tap][ci][co] wave-uniform -> s_load; shared across VPT voxels.
// ---------------------------------------------------------------------------
template<int ID,int IH,int IW,int OD,int OH,int OW,int CI,int CO,int COPT,int VPT,
         int KD,int KH,int KW,int SD,int SH,int SW,int PD,int PH,int PW,int DOWN>
__global__ __launch_bounds__(256)
void convd(const float* __restrict__ in, float* __restrict__ out,
           const unsigned char* __restrict__ min_, unsigned char* __restrict__ mout,
           const float* __restrict__ wp) {
  constexpr int NVOX = OD*OH*OW;
  constexpr int NTH  = (NVOX + VPT - 1) / VPT;
  int tid = blockIdx.x * blockDim.x + threadIdx.x;
  int cog = blockIdx.y;
  if (tid >= NTH) return;

  int ozv[VPT], oyv[VPT], oxv[VPT]; bool valid[VPT];
  #pragma unroll
  for (int k = 0; k < VPT; k++) {
    int v = tid + k*NTH;
    valid[k] = (v < NVOX);
    int vc = valid[k] ? v : 0;
    oxv[k] = vc % OW; int t = vc / OW; oyv[k] = t % OH; ozv[k] = t / OH;
  }
  float acc[VPT][COPT];
  #pragma unroll
  for (int k = 0; k < VPT; k++)
    #pragma unroll
    for (int c = 0; c < COPT; c++) acc[k][c] = 0.f;
  bool any[VPT];
  #pragma unroll
  for (int k = 0; k < VPT; k++) any[k] = false;

  #pragma unroll 1
  for (int kz = 0; kz < KD; kz++) {
    #pragma unroll 1
    for (int ky = 0; ky < KH; ky++) {
      #pragma unroll 1
      for (int kx = 0; kx < KW; kx++) {
        const float* wb = wp + ((size_t)((kz*KH + ky)*KW + kx) * CI) * CO + cog*COPT;
        bool ok[VPT]; const float* p[VPT];
        #pragma unroll
        for (int k = 0; k < VPT; k++) {
          int iz = ozv[k]*SD - PD + kz;
          int iy = oyv[k]*SH - PH + ky;
          int ix = oxv[k]*SW - PW + kx;
          ok[k] = ((unsigned)iz < (unsigned)ID) & ((unsigned)iy < (unsigned)IH)
                & ((unsigned)ix < (unsigned)IW);
          int izc = min(max(iz,0),ID-1), iyc = min(max(iy,0),IH-1), ixc = min(max(ix,0),IW-1);
          int ipos = (izc*IH + iyc)*IW + ixc;
          if constexpr (DOWN) { any[k] = any[k] || (ok[k] && (min_[ipos] != 0)); }
          p[k] = in + (size_t)ipos * CI;
        }
        #pragma unroll 2
        for (int cq = 0; cq < CI/4; cq++) {
          float a[VPT][4];
          #pragma unroll
          for (int k = 0; k < VPT; k++) {
            float4 av = *reinterpret_cast<const float4*>(p[k] + cq*4);
            a[k][0] = ok[k] ? av.x : 0.f;
            a[k][1] = ok[k] ? av.y : 0.f;
            a[k][2] = ok[k] ? av.z : 0.f;
            a[k][3] = ok[k] ? av.w : 0.f;
          }
          #pragma unroll
          for (int j = 0; j < 4; j++) {
            #pragma unroll
            for (int c = 0; c < COPT; c++) {
              float wv = wb[(cq*4 + j)*CO + c];
              #pragma unroll
              for (int k = 0; k < VPT; k++) acc[k][c] += a[k][j] * wv;
            }
          }
        }
      }
    }
  }
  #pragma unroll
  for (int k = 0; k < VPT; k++) {
    if (!valid[k]) continue;
    int v = tid + k*NTH;
    float* o = out + (size_t)v*CO + cog*COPT;
    #pragma unroll
    for (int c = 0; c < COPT; c++) o[c] = acc[k][c];
    if constexpr (DOWN) { if (cog == 0) mout[v] = any[k] ? 1 : 0; }
  }
}

// ---------------------------------------------------------------------------
// Masked BN stats: per-channel sum, sumsq, count.
// ---------------------------------------------------------------------------
template<int CO, int YD>
__global__ void bn_stats(const float* __restrict__ x, const unsigned char* __restrict__ m,
                         float* __restrict__ stats, int nvox) {
  int c  = threadIdx.x;
  int ty = threadIdx.y;
  float s = 0.f, q = 0.f, cnt = 0.f;
  for (int vox = blockIdx.x*YD + ty; vox < nvox; vox += gridDim.x*YD) {
    bool act = m ? (m[vox] != 0) : true;
    if (act) {
      float v = x[(size_t)vox*CO + c];
      s += v; q += v*v; cnt += 1.f;
    }
  }
  __shared__ float ls[YD][CO];
  __shared__ float lq[YD][CO];
  __shared__ float lc[YD];
  ls[ty][c] = s; lq[ty][c] = q;
  if (c == 0) lc[ty] = cnt;
  __syncthreads();
  if (ty == 0) {
    #pragma unroll
    for (int i = 1; i < YD; i++) { s += ls[i][c]; q += lq[i][c]; }
    atomicAdd(&stats[c], s);
    atomicAdd(&stats[CO + c], q);
    if (c == 0) {
      float tc = 0.f;
      #pragma unroll
      for (int i = 0; i < YD; i++) tc += lc[i];
      atomicAdd(&stats[2*CO], tc);
    }
  }
}

// ---------------------------------------------------------------------------
template<int CO>
__global__ __launch_bounds__(256)
void bn_apply(float* __restrict__ x, const unsigned char* __restrict__ m,
              const float* __restrict__ stats, const float* __restrict__ g,
              const float* __restrict__ b, int nvox) {
  int idx = blockIdx.x * blockDim.x + threadIdx.x;
  int vox = idx / CO, c = idx % CO;
  if (vox >= nvox) return;
  float cnt   = fmaxf(stats[2*CO], 1.f);
  float mean  = stats[c] / cnt;
  float var   = stats[CO + c] / cnt - mean*mean;
  float scale = g[c] * rsqrtf(var + EPSV);
  float v = (x[idx] - mean) * scale + b[c];
  v = fmaxf(v, 0.f);
  bool act = m ? (m[vox] != 0) : true;
  x[idx] = act ? v : 0.f;
}

// ---------------------------------------------------------------------------
__global__ __launch_bounds__(256)
void write_out(const float* __restrict__ x, float* __restrict__ out) {
  int idx = blockIdx.x * blockDim.x + threadIdx.x;
  if (idx >= 64*11*5*25) return;
  int y = idx % 25; int t = idx / 25;
  int z = t % 5;  t /= 5;
  int wx = t % 11; int c = t / 11;
  out[idx] = x[(((z*25 + y)*11) + wx)*64 + c];
}

// ---------------------------------------------------------------------------
extern "C" void kernel_launch(void* const* d_in, const int* in_sizes, int n_in,
                              void* d_out, int out_size, void* d_ws, size_t ws_size,
                              hipStream_t stream) {
  const float* vf    = (const float*)d_in[0];
  const int*   coors = (const int*)d_in[1];
  int n = in_sizes[0] / 16;

  // dict order is INTERLEAVED: vf, coors, bs, shape, (w0,g0,b0), (w1,g1,b1), ...
  const float *w[9], *g[9], *b[9];
  for (int i = 0; i < 9; i++) {
    w[i] = (const float*)d_in[4 + 3*i];
    g[i] = (const float*)d_in[5 + 3*i];
    b[i] = (const float*)d_in[6 + 3*i];
  }
  float* out = (float*)d_out;

  char* wsb = (char*)d_ws;
  size_t off = 0;
  auto alloc = [&](size_t bytes) -> void* {
    void* p = wsb + off;
    off += (bytes + 255) & ~(size_t)255;
    return p;
  };
  int*   grid0 = (int*)  alloc((size_t)40*200*200*4);
  float* wp    = (float*)alloc((size_t)454656*4);
  float* fA    = (float*)alloc((size_t)n*16*4);
  float* fB    = (float*)alloc((size_t)n*16*4);
  float* dA    = (float*)alloc((size_t)20*100*100*32*4);
  float* dB    = (float*)alloc((size_t)20*100*100*32*4);
  unsigned char* m2 = (unsigned char*)alloc(20*100*100);
  unsigned char* m4 = (unsigned char*)alloc(10*50*50);
  unsigned char* m6 = (unsigned char*)alloc(5*25*24);
  unsigned char* m8 = (unsigned char*)alloc(5*25*11);
  float* stats = (float*)alloc((size_t)9*160*4);

  float* st[9];
  for (int i = 0; i < 9; i++) st[i] = stats + i*160;

  hipMemsetAsync(grid0, 0xFF, (size_t)40*200*200*4, stream);
  hipMemsetAsync(stats, 0, (size_t)9*160*4, stream);

  WPtrs wps; for (int i = 0; i < 9; i++) wps.w[i] = w[i];
  repack_w<<<idiv(454656,256), 256, 0, stream>>>(wps, wp);
  scatter_grid<<<idiv(n,256), 256, 0, stream>>>(coors, grid0, n);

  const int WO0=0, WO1=6912, WO2=13824, WO3=27648, WO4=55296,
            WO5=110592, WO6=221184, WO7=331776, WO8=442368;

  // ---- L0, L1: sparse subm 16->16 ----
  subm16<<<idiv(n,256), 256, 0, stream>>>(vf, fA, coors, grid0, wp + WO0, n);
  bn_stats<16,16><<<imin(256, idiv(n,16)), dim3(16,16), 0, stream>>>(fA, nullptr, st[0], n);
  bn_apply<16><<<idiv(n*16,256), 256, 0, stream>>>(fA, nullptr, st[0], g[0], b[0], n);

  subm16<<<idiv(n,256), 256, 0, stream>>>(fA, fB, coors, grid0, wp + WO1, n);
  bn_stats<16,16><<<imin(256, idiv(n,16)), dim3(16,16), 0, stream>>>(fB, nullptr, st[1], n);
  bn_apply<16><<<idiv(n*16,256), 256, 0, stream>>>(fB, nullptr, st[1], g[1], b[1], n);

  // ---- L2: down 16->32 -> dense (20,100,100), COPT=16 x 2 groups ----
  down16to32<<<dim3(idiv(200000,256),2), 256, 0, stream>>>(fB, grid0, dA, m2, wp + WO2);
  bn_stats<32,8><<<imin(256, idiv(200000,8)), dim3(32,8), 0, stream>>>(dA, m2, st[2], 200000);
  bn_apply<32><<<idiv(200000*32,256), 256, 0, stream>>>(dA, m2, st[2], g[2], b[2], 200000);

  // ---- L3: subm 32->32 dense, VPT=2 x COPT=16 ----
  convd<20,100,100, 20,100,100, 32,32,16,2, 3,3,3, 1,1,1, 1,1,1, 0>
      <<<dim3(idiv(100000,256),2), 256, 0, stream>>>(dA, dB, nullptr, nullptr, wp + WO3);
  bn_stats<32,8><<<imin(256, idiv(200000,8)), dim3(32,8), 0, stream>>>(dB, m2, st[3], 200000);
  bn_apply<32><<<idiv(200000*32,256), 256, 0, stream>>>(dB, m2, st[3], g[3], b[3], 200000);

  // ---- L4: down 32->64 -> (10,50,50), COPT=16 x 4 groups ----
  convd<20,100,100, 10,50,50, 32,64,16,1, 3,3,3, 2,2,2, 1,1,1, 1>
      <<<dim3(idiv(25000,256),4), 256, 0, stream>>>(dB, dA, m2, m4, wp + WO4);
  bn_stats<64,4><<<imin(256, idiv(25000,4)), dim3(64,4), 0, stream>>>(dA, m4, st[4], 25000);
  bn_apply<64><<<idiv(25000*64,256), 256, 0, stream>>>(dA, m4, st[4], g[4], b[4], 25000);

  // ---- L5: subm 64->64, COPT=16 x 4 groups ----
  convd<10,50,50, 10,50,50, 64,64,16,1, 3,3,3, 1,1,1, 1,1,1, 0>
      <<<dim3(idiv(25000,256),4), 256, 0, stream>>>(dA, dB, nullptr, nullptr, wp + WO5);
  bn_stats<64,4><<<imin(256, idiv(25000,4)), dim3(64,4), 0, stream>>>(dB, m4, st[5], 25000);
  bn_apply<64><<<idiv(25000*64,256), 256, 0, stream>>>(dB, m4, st[5], g[5], b[5], 25000);

  // ---- L6: down 64->64 s(2,2,2) p(1,1,0) -> (5,25,24), COPT=8 x 8 ----
  convd<10,50,50, 5,25,24, 64,64,8,1, 3,3,3, 2,2,2, 1,1,0, 1>
      <<<dim3(idiv(3000,256),8), 256, 0, stream>>>(dB, dA, m4, m6, wp + WO6);
  bn_stats<64,4><<<imin(256, idiv(3000,4)), dim3(64,4), 0, stream>>>(dA, m6, st[6], 3000);
  bn_apply<64><<<idiv(3000*64,256), 256, 0, stream>>>(dA, m6, st[6], g[6], b[6], 3000);

  // ---- L7: subm 64->64, COPT=8 x 8 ----
  convd<5,25,24, 5,25,24, 64,64,8,1, 3,3,3, 1,1,1, 1,1,1, 0>
      <<<dim3(idiv(3000,256),8), 256, 0, stream>>>(dA, dB, nullptr, nullptr, wp + WO7);
  bn_stats<64,4><<<imin(256, idiv(3000,4)), dim3(64,4), 0, stream>>>(dB, m6, st[7], 3000);
  bn_apply<64><<<idiv(3000*64,256), 256, 0, stream>>>(dB, m6, st[7], g[7], b[7], 3000);

  // ---- L8: down 64->64 k(1,1,3) s(1,1,2) -> (5,25,11), COPT=8 x 8 ----
  convd<5,25,24, 5,25,11, 64,64,8,1, 1,1,3, 1,1,2, 0,0,0, 1>
      <<<dim3(idiv(1375,256),8), 256, 0, stream>>>(dB, dA, m6, m8, wp + WO8);
  bn_stats<64,4><<<imin(256, idiv(1375,4)), dim3(64,4), 0, stream>>>(dA, m8, st[8], 1375);
  bn_apply<64><<<idiv(1375*64,256), 256, 0, stream>>>(dA, m8, st[8], g[8], b[8], 1375);

  write_out<<<idiv(88000,256), 256, 0, stream>>>(dA, out);
}

// Round 4
// 1457.023 us; speedup vs baseline: 1.5491x; 1.1516x over previous
//
#include <hip/hip_runtime.h>
#include <cstddef>

#define EPSV 0.001f

static inline int idiv(int a, int b){ return (a + b - 1) / b; }
static inline int imin(int a, int b){ return a < b ? a : b; }

// ---------------------------------------------------------------------------
// Weight repack: w (CO,CI,kz,ky,kx) -> wp[(tap*CI+ci)*CO + co]
// ---------------------------------------------------------------------------
struct WPtrs { const float* w[9]; };

__global__ __launch_bounds__(256)
void repack_w(WPtrs ws, float* __restrict__ wp) {
  constexpr int off[10] = {0,6912,13824,27648,55296,110592,221184,331776,442368,454656};
  constexpr int COs[9] = {16,16,32,32,64,64,64,64,64};
  constexpr int CIs[9] = {16,16,16,32,32,64,64,64,64};
  constexpr int NTs[9] = {27,27,27,27,27,27,27,27,3};
  int idx = blockIdx.x * blockDim.x + threadIdx.x;
  if (idx >= off[9]) return;
  int L = 0;
  #pragma unroll
  for (int k = 0; k < 9; k++) if (idx >= off[k+1]) L = k + 1;
  int r  = idx - off[L];
  int CO = COs[L], CI = CIs[L], NT = NTs[L];
  int co = r % CO; int t = r / CO; int ci = t % CI; int tap = t / CI;
  wp[idx] = ws.w[L][(co*CI + ci)*NT + tap];
}

// ---------------------------------------------------------------------------
__global__ __launch_bounds__(256)
void scatter_grid(const int* __restrict__ coors, int* __restrict__ grid, int n) {
  int i = blockIdx.x * blockDim.x + threadIdx.x;
  if (i >= n) return;
  int z = coors[4*i+1], y = coors[4*i+2], x = coors[4*i+3];
  grid[(z*200 + y)*200 + x] = i;
}

// ---------------------------------------------------------------------------
// Sparse submanifold 3x3x3 conv, 16->16, over active voxel list.
// ---------------------------------------------------------------------------
__global__ __launch_bounds__(256)
void subm16(const float* __restrict__ fin, float* __restrict__ fout,
            const int* __restrict__ coors, const int* __restrict__ grid,
            const float* __restrict__ wp, int n) {
  int i = blockIdx.x * blockDim.x + threadIdx.x;
  if (i >= n) return;
  int z = coors[4*i+1], y = coors[4*i+2], x = coors[4*i+3];
  float acc[16];
  #pragma unroll
  for (int c = 0; c < 16; c++) acc[c] = 0.f;
  for (int kz = 0; kz < 3; kz++) {
    int iz = z + kz - 1; if ((unsigned)iz >= 40u) continue;
    for (int ky = 0; ky < 3; ky++) {
      int iy = y + ky - 1; if ((unsigned)iy >= 200u) continue;
      for (int kx = 0; kx < 3; kx++) {
        int ix = x + kx - 1; if ((unsigned)ix >= 200u) continue;
        int j = grid[(iz*200 + iy)*200 + ix];
        if (j < 0) continue;
        int tap = (kz*3 + ky)*3 + kx;
        const float* fj = fin + (size_t)j*16;
        const float* wb = wp + tap*16*16;
        #pragma unroll
        for (int cq = 0; cq < 4; cq++) {
          float4 av = *reinterpret_cast<const float4*>(fj + cq*4);
          float aj[4] = {av.x, av.y, av.z, av.w};
          #pragma unroll
          for (int j4 = 0; j4 < 4; j4++) {
            #pragma unroll
            for (int c = 0; c < 16; c++) acc[c] += aj[j4] * wb[(cq*4+j4)*16 + c];
          }
        }
      }
    }
  }
  float* o = fout + (size_t)i*16;
  #pragma unroll
  for (int c = 0; c < 16; c++) o[c] = acc[c];
}

// ---------------------------------------------------------------------------
// L2: strided (2,2,2) pad(1,1,1) 3x3x3 conv 16->32, sparse -> dense
// channels-last (20,100,100,32) + new mask. COPT=16, grid.y=2.
// ---------------------------------------------------------------------------
__global__ __launch_bounds__(256)
void down16to32(const float* __restrict__ fin, const int* __restrict__ grid,
                float* __restrict__ out, unsigned char* __restrict__ mout,
                const float* __restrict__ wp) {
  constexpr int OD = 20, OH = 100, OW = 100, COPT = 16;
  int vox = blockIdx.x * blockDim.x + threadIdx.x;
  int cog = blockIdx.y;
  if (vox >= OD*OH*OW) return;
  int ox = vox % OW; int t = vox / OW; int oy = t % OH; int oz = t / OH;
  float acc[COPT];
  #pragma unroll
  for (int c = 0; c < COPT; c++) acc[c] = 0.f;
  bool any = false;
  for (int kz = 0; kz < 3; kz++) {
    int iz = oz*2 - 1 + kz; if ((unsigned)iz >= 40u) continue;
    for (int ky = 0; ky < 3; ky++) {
      int iy = oy*2 - 1 + ky; if ((unsigned)iy >= 200u) continue;
      for (int kx = 0; kx < 3; kx++) {
        int ix = ox*2 - 1 + kx; if ((unsigned)ix >= 200u) continue;
        int j = grid[(iz*200 + iy)*200 + ix];
        if (j < 0) continue;
        any = true;
        int tap = (kz*3 + ky)*3 + kx;
        const float* fj = fin + (size_t)j*16;
        const float* wb = wp + (size_t)tap*16*32 + cog*COPT;
        #pragma unroll
        for (int cq = 0; cq < 4; cq++) {
          float4 av = *reinterpret_cast<const float4*>(fj + cq*4);
          float aj[4] = {av.x, av.y, av.z, av.w};
          #pragma unroll
          for (int j4 = 0; j4 < 4; j4++) {
            #pragma unroll
            for (int c = 0; c < COPT; c++) acc[c] += aj[j4] * wb[(cq*4+j4)*32 + c];
          }
        }
      }
    }
  }
  float* o = out + (size_t)vox*32 + cog*COPT;
  #pragma unroll
  for (int c = 0; c < COPT; c++) o[c] = acc[c];
  if (cog == 0) mout[vox] = any ? 1 : 0;
}

// ---------------------------------------------------------------------------
// LDS implicit-GEMM dense conv, channels-last.
// Block = 256 threads = G co-groups x S slots (g fastest). Per tap:
//   stage shifted A-tile (VT x CI, coalesced, XOR-swizzled) + W-tap (CI x CO)
//   into LDS, then each thread computes VX voxels x CO2 channels from LDS.
// Thread's voxels: r = s + S*u  (keeps (r&7) = s&7 -> conflict-free reads).
// ---------------------------------------------------------------------------
template<int ID,int IH,int IW,int OD,int OH,int OW,int CI,int CO,
         int S,int VX,int CO2,
         int KD,int KH,int KW,int SD,int SH,int SW,int PD,int PH,int PW>
__global__ __launch_bounds__(256)
void convg(const float* __restrict__ in, float* __restrict__ out,
           const float* __restrict__ wp) {
  constexpr int G    = 256 / S;
  static_assert(G * CO2 == CO, "co tiling mismatch");
  constexpr int VT   = S * VX;
  constexpr int NVOX = OD*OH*OW;
  __shared__ float a_lds[VT * CI];
  __shared__ float w_lds[CI * CO];

  const int g   = threadIdx.x % G;
  const int s   = threadIdx.x / G;
  const int co0 = g * CO2;
  const int vbase = blockIdx.x * VT;

  float acc[VX][CO2];
  #pragma unroll
  for (int u = 0; u < VX; u++)
    #pragma unroll
    for (int cc = 0; cc < CO2; cc++) acc[u][cc] = 0.f;

  constexpr int CI4N = CI / 4;      // float4s per voxel row
  constexpr int VST  = 256 / CI4N;  // voxels staged per step
  const int sv  = threadIdx.x / CI4N;
  const int sc4 = threadIdx.x % CI4N;

  #pragma unroll 1
  for (int kz = 0; kz < KD; kz++) {
    #pragma unroll 1
    for (int ky = 0; ky < KH; ky++) {
      #pragma unroll 1
      for (int kx = 0; kx < KW; kx++) {
        __syncthreads();
        // ---- stage W (CI x CO, co fastest — matches wp layout) ----
        const float* wt = wp + (size_t)((kz*KH + ky)*KW + kx) * CI * CO;
        #pragma unroll
        for (int i = 0; i < CI*CO/4/256; i++) {
          int idx = threadIdx.x + i*256;
          *reinterpret_cast<float4*>(&w_lds[idx*4]) =
              *reinterpret_cast<const float4*>(wt + idx*4);
        }
        // ---- stage A (VT voxels x CI, gathered + swizzled) ----
        #pragma unroll
        for (int rsub = 0; rsub < VT/VST; rsub++) {
          int vox = rsub*VST + sv;
          int gv  = vbase + vox;
          int vc  = gv < NVOX ? gv : 0;
          int ox = vc % OW; int tt = vc / OW; int oy = tt % OH; int oz = tt / OH;
          int iz = oz*SD - PD + kz;
          int iy = oy*SH - PH + ky;
          int ix = ox*SW - PW + kx;
          bool ok = (gv < NVOX) & ((unsigned)iz < (unsigned)ID)
                  & ((unsigned)iy < (unsigned)IH) & ((unsigned)ix < (unsigned)IW);
          float4 v = make_float4(0.f,0.f,0.f,0.f);
          if (ok) {
            int ipos = (iz*IH + iy)*IW + ix;
            v = *reinterpret_cast<const float4*>(in + (size_t)ipos*CI + sc4*4);
          }
          int dw = vox*CI + ((sc4*4) ^ ((vox & 7) << 2));
          *reinterpret_cast<float4*>(&a_lds[dw]) = v;
        }
        __syncthreads();
        // ---- compute from LDS ----
        #pragma unroll
        for (int c4 = 0; c4 < CI/4; c4++) {
          float wr[4][CO2];
          #pragma unroll
          for (int jj = 0; jj < 4; jj++)
            #pragma unroll
            for (int q = 0; q < CO2/4; q++) {
              float4 wv = *reinterpret_cast<const float4*>(
                  &w_lds[(c4*4 + jj)*CO + co0 + q*4]);
              wr[jj][q*4+0] = wv.x; wr[jj][q*4+1] = wv.y;
              wr[jj][q*4+2] = wv.z; wr[jj][q*4+3] = wv.w;
            }
          #pragma unroll
          for (int u = 0; u < VX; u++) {
            int r = s + S*u;
            float4 a4 = *reinterpret_cast<const float4*>(
                &a_lds[r*CI + ((c4*4) ^ ((r & 7) << 2))]);
            float av[4] = {a4.x, a4.y, a4.z, a4.w};
            #pragma unroll
            for (int jj = 0; jj < 4; jj++)
              #pragma unroll
              for (int cc = 0; cc < CO2; cc++)
                acc[u][cc] += av[jj] * wr[jj][cc];
          }
        }
      }
    }
  }
  // ---- epilogue ----
  #pragma unroll
  for (int u = 0; u < VX; u++) {
    int gv = vbase + s + S*u;
    if (gv >= NVOX) continue;
    float* o = out + (size_t)gv*CO + co0;
    #pragma unroll
    for (int q = 0; q < CO2/4; q++) {
      float4 v = make_float4(acc[u][q*4+0], acc[u][q*4+1],
                             acc[u][q*4+2], acc[u][q*4+3]);
      *reinterpret_cast<float4*>(o + q*4) = v;
    }
  }
}

// ---------------------------------------------------------------------------
// Downsample mask: mout[v] = OR over taps of in-bounds min_.
// ---------------------------------------------------------------------------
template<int ID,int IH,int IW,int OD,int OH,int OW,int KD,int KH,int KW,
         int SD,int SH,int SW,int PD,int PH,int PW>
__global__ __launch_bounds__(256)
void mask_down(const unsigned char* __restrict__ min_, unsigned char* __restrict__ mout) {
  int v = blockIdx.x * blockDim.x + threadIdx.x;
  if (v >= OD*OH*OW) return;
  int ox = v % OW; int t = v / OW; int oy = t % OH; int oz = t / OH;
  bool any = false;
  for (int kz = 0; kz < KD; kz++) {
    int iz = oz*SD - PD + kz; if ((unsigned)iz >= (unsigned)ID) continue;
    for (int ky = 0; ky < KH; ky++) {
      int iy = oy*SH - PH + ky; if ((unsigned)iy >= (unsigned)IH) continue;
      for (int kx = 0; kx < KW; kx++) {
        int ix = ox*SW - PW + kx; if ((unsigned)ix >= (unsigned)IW) continue;
        any = any || (min_[(iz*IH + iy)*IW + ix] != 0);
      }
    }
  }
  mout[v] = any ? 1 : 0;
}

// ---------------------------------------------------------------------------
// Dense direct conv (small tail layers), channels-last, COPT per blockIdx.y.
// ---------------------------------------------------------------------------
template<int ID,int IH,int IW,int OD,int OH,int OW,int CI,int CO,int COPT,
         int KD,int KH,int KW,int SD,int SH,int SW,int PD,int PH,int PW,int DOWN>
__global__ __launch_bounds__(256)
void convd(const float* __restrict__ in, float* __restrict__ out,
           const unsigned char* __restrict__ min_, unsigned char* __restrict__ mout,
           const float* __restrict__ wp) {
  constexpr int NVOX = OD*OH*OW;
  int vox = blockIdx.x * blockDim.x + threadIdx.x;
  int cog = blockIdx.y;
  if (vox >= NVOX) return;
  int ox = vox % OW; int t = vox / OW; int oy = t % OH; int oz = t / OH;
  float acc[COPT];
  #pragma unroll
  for (int c = 0; c < COPT; c++) acc[c] = 0.f;
  bool any = false;
  #pragma unroll 1
  for (int kz = 0; kz < KD; kz++) {
    #pragma unroll 1
    for (int ky = 0; ky < KH; ky++) {
      #pragma unroll 1
      for (int kx = 0; kx < KW; kx++) {
        int iz = oz*SD - PD + kz;
        int iy = oy*SH - PH + ky;
        int ix = ox*SW - PW + kx;
        bool ok = ((unsigned)iz < (unsigned)ID) & ((unsigned)iy < (unsigned)IH)
                & ((unsigned)ix < (unsigned)IW);
        int izc = min(max(iz,0),ID-1), iyc = min(max(iy,0),IH-1), ixc = min(max(ix,0),IW-1);
        int ipos = (izc*IH + iyc)*IW + ixc;
        if constexpr (DOWN) { any = any || (ok && (min_[ipos] != 0)); }
        const float* p = in + (size_t)ipos*CI;
        const float* wb = wp + ((size_t)((kz*KH + ky)*KW + kx) * CI) * CO + cog*COPT;
        #pragma unroll 4
        for (int ci = 0; ci < CI; ci++) {
          float v = ok ? p[ci] : 0.f;
          #pragma unroll
          for (int c = 0; c < COPT; c++) acc[c] += v * wb[ci*CO + c];
        }
      }
    }
  }
  float* o = out + (size_t)vox*CO + cog*COPT;
  #pragma unroll
  for (int c = 0; c < COPT; c++) o[c] = acc[c];
  if constexpr (DOWN) { if (cog == 0) mout[vox] = any ? 1 : 0; }
}

// ---------------------------------------------------------------------------
// Masked BN stats: per-channel sum, sumsq, count.
// ---------------------------------------------------------------------------
template<int CO, int YD>
__global__ void bn_stats(const float* __restrict__ x, const unsigned char* __restrict__ m,
                         float* __restrict__ stats, int nvox) {
  int c  = threadIdx.x;
  int ty = threadIdx.y;
  float s = 0.f, q = 0.f, cnt = 0.f;
  for (int vox = blockIdx.x*YD + ty; vox < nvox; vox += gridDim.x*YD) {
    bool act = m ? (m[vox] != 0) : true;
    if (act) {
      float v = x[(size_t)vox*CO + c];
      s += v; q += v*v; cnt += 1.f;
    }
  }
  __shared__ float ls[YD][CO];
  __shared__ float lq[YD][CO];
  __shared__ float lc[YD];
  ls[ty][c] = s; lq[ty][c] = q;
  if (c == 0) lc[ty] = cnt;
  __syncthreads();
  if (ty == 0) {
    #pragma unroll
    for (int i = 1; i < YD; i++) { s += ls[i][c]; q += lq[i][c]; }
    atomicAdd(&stats[c], s);
    atomicAdd(&stats[CO + c], q);
    if (c == 0) {
      float tc = 0.f;
      #pragma unroll
      for (int i = 0; i < YD; i++) tc += lc[i];
      atomicAdd(&stats[2*CO], tc);
    }
  }
}

// ---------------------------------------------------------------------------
template<int CO>
__global__ __launch_bounds__(256)
void bn_apply(float* __restrict__ x, const unsigned char* __restrict__ m,
              const float* __restrict__ stats, const float* __restrict__ g,
              const float* __restrict__ b, int nvox) {
  int idx = blockIdx.x * blockDim.x + threadIdx.x;
  int vox = idx / CO, c = idx % CO;
  if (vox >= nvox) return;
  float cnt   = fmaxf(stats[2*CO], 1.f);
  float mean  = stats[c] / cnt;
  float var   = stats[CO + c] / cnt - mean*mean;
  float scale = g[c] * rsqrtf(var + EPSV);
  float v = (x[idx] - mean) * scale + b[c];
  v = fmaxf(v, 0.f);
  bool act = m ? (m[vox] != 0) : true;
  x[idx] = act ? v : 0.f;
}

// ---------------------------------------------------------------------------
__global__ __launch_bounds__(256)
void write_out(const float* __restrict__ x, float* __restrict__ out) {
  int idx = blockIdx.x * blockDim.x + threadIdx.x;
  if (idx >= 64*11*5*25) return;
  int y = idx % 25; int t = idx / 25;
  int z = t % 5;  t /= 5;
  int wx = t % 11; int c = t / 11;
  out[idx] = x[(((z*25 + y)*11) + wx)*64 + c];
}

// ---------------------------------------------------------------------------
extern "C" void kernel_launch(void* const* d_in, const int* in_sizes, int n_in,
                              void* d_out, int out_size, void* d_ws, size_t ws_size,
                              hipStream_t stream) {
  const float* vf    = (const float*)d_in[0];
  const int*   coors = (const int*)d_in[1];
  int n = in_sizes[0] / 16;

  // dict order is INTERLEAVED: vf, coors, bs, shape, (w0,g0,b0), (w1,g1,b1), ...
  const float *w[9], *g[9], *b[9];
  for (int i = 0; i < 9; i++) {
    w[i] = (const float*)d_in[4 + 3*i];
    g[i] = (const float*)d_in[5 + 3*i];
    b[i] = (const float*)d_in[6 + 3*i];
  }
  float* out = (float*)d_out;

  char* wsb = (char*)d_ws;
  size_t off = 0;
  auto alloc = [&](size_t bytes) -> void* {
    void* p = wsb + off;
    off += (bytes + 255) & ~(size_t)255;
    return p;
  };
  int*   grid0 = (int*)  alloc((size_t)40*200*200*4);
  float* wp    = (float*)alloc((size_t)454656*4);
  float* fA    = (float*)alloc((size_t)n*16*4);
  float* fB    = (float*)alloc((size_t)n*16*4);
  float* dA    = (float*)alloc((size_t)20*100*100*32*4);
  float* dB    = (float*)alloc((size_t)20*100*100*32*4);
  unsigned char* m2 = (unsigned char*)alloc(20*100*100);
  unsigned char* m4 = (unsigned char*)alloc(10*50*50);
  unsigned char* m6 = (unsigned char*)alloc(5*25*24);
  unsigned char* m8 = (unsigned char*)alloc(5*25*11);
  float* stats = (float*)alloc((size_t)9*160*4);

  float* st[9];
  for (int i = 0; i < 9; i++) st[i] = stats + i*160;

  hipMemsetAsync(grid0, 0xFF, (size_t)40*200*200*4, stream);
  hipMemsetAsync(stats, 0, (size_t)9*160*4, stream);

  WPtrs wps; for (int i = 0; i < 9; i++) wps.w[i] = w[i];
  repack_w<<<idiv(454656,256), 256, 0, stream>>>(wps, wp);
  scatter_grid<<<idiv(n,256), 256, 0, stream>>>(coors, grid0, n);

  const int WO0=0, WO1=6912, WO2=13824, WO3=27648, WO4=55296,
            WO5=110592, WO6=221184, WO7=331776, WO8=442368;

  // ---- L0, L1: sparse subm 16->16 ----
  subm16<<<idiv(n,256), 256, 0, stream>>>(vf, fA, coors, grid0, wp + WO0, n);
  bn_stats<16,16><<<imin(256, idiv(n,16)), dim3(16,16), 0, stream>>>(fA, nullptr, st[0], n);
  bn_apply<16><<<idiv(n*16,256), 256, 0, stream>>>(fA, nullptr, st[0], g[0], b[0], n);

  subm16<<<idiv(n,256), 256, 0, stream>>>(fA, fB, coors, grid0, wp + WO1, n);
  bn_stats<16,16><<<imin(256, idiv(n,16)), dim3(16,16), 0, stream>>>(fB, nullptr, st[1], n);
  bn_apply<16><<<idiv(n*16,256), 256, 0, stream>>>(fB, nullptr, st[1], g[1], b[1], n);

  // ---- L2: down 16->32 -> dense (20,100,100), COPT=16 x 2 groups ----
  down16to32<<<dim3(idiv(200000,256),2), 256, 0, stream>>>(fB, grid0, dA, m2, wp + WO2);
  bn_stats<32,8><<<imin(256, idiv(200000,8)), dim3(32,8), 0, stream>>>(dA, m2, st[2], 200000);
  bn_apply<32><<<idiv(200000*32,256), 256, 0, stream>>>(dA, m2, st[2], g[2], b[2], 200000);

  // ---- L3: subm 32->32 dense, LDS implicit-GEMM (VT=256, S=32,VX=8,CO2=4) ----
  convg<20,100,100, 20,100,100, 32,32, 32,8,4, 3,3,3, 1,1,1, 1,1,1>
      <<<idiv(200000,256), 256, 0, stream>>>(dA, dB, wp + WO3);
  bn_stats<32,8><<<imin(256, idiv(200000,8)), dim3(32,8), 0, stream>>>(dB, m2, st[3], 200000);
  bn_apply<32><<<idiv(200000*32,256), 256, 0, stream>>>(dB, m2, st[3], g[3], b[3], 200000);

  // ---- L4: down 32->64 -> (10,50,50), VT=128 (S=32,VX=4,CO2=8) + mask ----
  convg<20,100,100, 10,50,50, 32,64, 32,4,8, 3,3,3, 2,2,2, 1,1,1>
      <<<idiv(25000,128), 256, 0, stream>>>(dB, dA, wp + WO4);
  mask_down<20,100,100, 10,50,50, 3,3,3, 2,2,2, 1,1,1>
      <<<idiv(25000,256), 256, 0, stream>>>(m2, m4);
  bn_stats<64,4><<<imin(256, idiv(25000,4)), dim3(64,4), 0, stream>>>(dA, m4, st[4], 25000);
  bn_apply<64><<<idiv(25000*64,256), 256, 0, stream>>>(dA, m4, st[4], g[4], b[4], 25000);

  // ---- L5: subm 64->64, VT=128 (S=16,VX=8,CO2=4) ----
  convg<10,50,50, 10,50,50, 64,64, 16,8,4, 3,3,3, 1,1,1, 1,1,1>
      <<<idiv(25000,128), 256, 0, stream>>>(dA, dB, wp + WO5);
  bn_stats<64,4><<<imin(256, idiv(25000,4)), dim3(64,4), 0, stream>>>(dB, m4, st[5], 25000);
  bn_apply<64><<<idiv(25000*64,256), 256, 0, stream>>>(dB, m4, st[5], g[5], b[5], 25000);

  // ---- L6: down 64->64 s(2,2,2) p(1,1,0) -> (5,25,24), COPT=8 x 8 ----
  convd<10,50,50, 5,25,24, 64,64,8, 3,3,3, 2,2,2, 1,1,0, 1>
      <<<dim3(idiv(3000,256),8), 256, 0, stream>>>(dB, dA, m4, m6, wp + WO6);
  bn_stats<64,4><<<imin(256, idiv(3000,4)), dim3(64,4), 0, stream>>>(dA, m6, st[6], 3000);
  bn_apply<64><<<idiv(3000*64,256), 256, 0, stream>>>(dA, m6, st[6], g[6], b[6], 3000);

  // ---- L7: subm 64->64, COPT=8 x 8 ----
  convd<5,25,24, 5,25,24, 64,64,8, 3,3,3, 1,1,1, 1,1,1, 0>
      <<<dim3(idiv(3000,256),8), 256, 0, stream>>>(dA, dB, nullptr, nullptr, wp + WO7);
  bn_stats<64,4><<<imin(256, idiv(3000,4)), dim3(64,4), 0, stream>>>(dB, m6, st[7], 3000);
  bn_apply<64><<<idiv(3000*64,256), 256, 0, stream>>>(dB, m6, st[7], g[7], b[7], 3000);

  // ---- L8: down 64->64 k(1,1,3) s(1,1,2) -> (5,25,11), COPT=8 x 8 ----
  convd<5,25,24, 5,25,11, 64,64,8, 1,1,3, 1,1,2, 0,0,0, 1>
      <<<dim3(idiv(1375,256),8), 256, 0, stream>>>(dB, dA, m6, m8, wp + WO8);
  bn_stats<64,4><<<imin(256, idiv(1375,4)), dim3(64,4), 0, stream>>>(dA, m8, st[8], 1375);
  bn_apply<64><<<idiv(1375*64,256), 256, 0, stream>>>(dA, m8, st[8], g[8], b[8], 1375);

  write_out<<<idiv(88000,256), 256, 0, stream>>>(dA, out);
}

// Round 6
// 1188.244 us; speedup vs baseline: 1.8995x; 1.2262x over previous
//
#include <hip/hip_runtime.h>
#include <cstddef>

#define EPSV 0.001f

static inline int idiv(int a, int b){ return (a + b - 1) / b; }
static inline int imin(int a, int b){ return a < b ? a : b; }

// ---------------------------------------------------------------------------
// Weight repack: w (CO,CI,kz,ky,kx) -> wp[(tap*CI+ci)*CO + co]
// ---------------------------------------------------------------------------
struct WPtrs { const float* w[9]; };

__global__ __launch_bounds__(256)
void repack_w(WPtrs ws, float* __restrict__ wp) {
  constexpr int off[10] = {0,6912,13824,27648,55296,110592,221184,331776,442368,454656};
  constexpr int COs[9] = {16,16,32,32,64,64,64,64,64};
  constexpr int CIs[9] = {16,16,16,32,32,64,64,64,64};
  constexpr int NTs[9] = {27,27,27,27,27,27,27,27,3};
  int idx = blockIdx.x * blockDim.x + threadIdx.x;
  if (idx >= off[9]) return;
  int L = 0;
  #pragma unroll
  for (int k = 0; k < 9; k++) if (idx >= off[k+1]) L = k + 1;
  int r  = idx - off[L];
  int CO = COs[L], CI = CIs[L], NT = NTs[L];
  int co = r % CO; int t = r / CO; int ci = t % CI; int tap = t / CI;
  wp[idx] = ws.w[L][(co*CI + ci)*NT + tap];
}

// ---------------------------------------------------------------------------
// Tail-layer weight repack: w (64,64,taps) -> wq[(tap*64+co)*64+ci]
// for layers 6,7 (27 taps) and 8 (3 taps), concatenated.
// ---------------------------------------------------------------------------
__global__ __launch_bounds__(256)
void repack_wq(const float* __restrict__ w6, const float* __restrict__ w7,
               const float* __restrict__ w8, float* __restrict__ wq) {
  constexpr int N6 = 110592, N7 = 110592, N8 = 12288;
  int idx = blockIdx.x * blockDim.x + threadIdx.x;
  if (idx >= N6 + N7 + N8) return;
  const float* src; int r; int NT;
  if (idx < N6)            { src = w6; r = idx;          NT = 27; }
  else if (idx < N6 + N7)  { src = w7; r = idx - N6;     NT = 27; }
  else                     { src = w8; r = idx - N6 - N7; NT = 3; }
  int ci = r % 64; int t = r / 64; int co = t % 64; int tap = t / 64;
  wq[idx] = src[(co*64 + ci)*NT + tap];
}

// ---------------------------------------------------------------------------
__global__ __launch_bounds__(256)
void scatter_grid(const int* __restrict__ coors, int* __restrict__ grid, int n) {
  int i = blockIdx.x * blockDim.x + threadIdx.x;
  if (i >= n) return;
  int z = coors[4*i+1], y = coors[4*i+2], x = coors[4*i+3];
  grid[(z*200 + y)*200 + x] = i;
}

// ---------------------------------------------------------------------------
// Sparse submanifold 3x3x3 conv, 16->16, over active voxel list.
// ---------------------------------------------------------------------------
__global__ __launch_bounds__(256)
void subm16(const float* __restrict__ fin, float* __restrict__ fout,
            const int* __restrict__ coors, const int* __restrict__ grid,
            const float* __restrict__ wp, int n) {
  int i = blockIdx.x * blockDim.x + threadIdx.x;
  if (i >= n) return;
  int z = coors[4*i+1], y = coors[4*i+2], x = coors[4*i+3];
  float acc[16];
  #pragma unroll
  for (int c = 0; c < 16; c++) acc[c] = 0.f;
  for (int kz = 0; kz < 3; kz++) {
    int iz = z + kz - 1; if ((unsigned)iz >= 40u) continue;
    for (int ky = 0; ky < 3; ky++) {
      int iy = y + ky - 1; if ((unsigned)iy >= 200u) continue;
      for (int kx = 0; kx < 3; kx++) {
        int ix = x + kx - 1; if ((unsigned)ix >= 200u) continue;
        int j = grid[(iz*200 + iy)*200 + ix];
        if (j < 0) continue;
        int tap = (kz*3 + ky)*3 + kx;
        const float* fj = fin + (size_t)j*16;
        const float* wb = wp + tap*16*16;
        #pragma unroll
        for (int cq = 0; cq < 4; cq++) {
          float4 av = *reinterpret_cast<const float4*>(fj + cq*4);
          float aj[4] = {av.x, av.y, av.z, av.w};
          #pragma unroll
          for (int j4 = 0; j4 < 4; j4++) {
            #pragma unroll
            for (int c = 0; c < 16; c++) acc[c] += aj[j4] * wb[(cq*4+j4)*16 + c];
          }
        }
      }
    }
  }
  float* o = fout + (size_t)i*16;
  #pragma unroll
  for (int c = 0; c < 16; c++) o[c] = acc[c];
}

// ---------------------------------------------------------------------------
// L2: strided (2,2,2) pad(1,1,1) 3x3x3 conv 16->32, sparse -> dense
// channels-last (20,100,100,32) + new mask. COPT=16, grid.y=2.
// ---------------------------------------------------------------------------
__global__ __launch_bounds__(256)
void down16to32(const float* __restrict__ fin, const int* __restrict__ grid,
                float* __restrict__ out, unsigned char* __restrict__ mout,
                const float* __restrict__ wp) {
  constexpr int OD = 20, OH = 100, OW = 100, COPT = 16;
  int vox = blockIdx.x * blockDim.x + threadIdx.x;
  int cog = blockIdx.y;
  if (vox >= OD*OH*OW) return;
  int ox = vox % OW; int t = vox / OW; int oy = t % OH; int oz = t / OH;
  float acc[COPT];
  #pragma unroll
  for (int c = 0; c < COPT; c++) acc[c] = 0.f;
  bool any = false;
  for (int kz = 0; kz < 3; kz++) {
    int iz = oz*2 - 1 + kz; if ((unsigned)iz >= 40u) continue;
    for (int ky = 0; ky < 3; ky++) {
      int iy = oy*2 - 1 + ky; if ((unsigned)iy >= 200u) continue;
      for (int kx = 0; kx < 3; kx++) {
        int ix = ox*2 - 1 + kx; if ((unsigned)ix >= 200u) continue;
        int j = grid[(iz*200 + iy)*200 + ix];
        if (j < 0) continue;
        any = true;
        int tap = (kz*3 + ky)*3 + kx;
        const float* fj = fin + (size_t)j*16;
        const float* wb = wp + (size_t)tap*16*32 + cog*COPT;
        #pragma unroll
        for (int cq = 0; cq < 4; cq++) {
          float4 av = *reinterpret_cast<const float4*>(fj + cq*4);
          float aj[4] = {av.x, av.y, av.z, av.w};
          #pragma unroll
          for (int j4 = 0; j4 < 4; j4++) {
            #pragma unroll
            for (int c = 0; c < COPT; c++) acc[c] += aj[j4] * wb[(cq*4+j4)*32 + c];
          }
        }
      }
    }
  }
  float* o = out + (size_t)vox*32 + cog*COPT;
  #pragma unroll
  for (int c = 0; c < COPT; c++) o[c] = acc[c];
  if (cog == 0) mout[vox] = any ? 1 : 0;
}

// ---------------------------------------------------------------------------
// LDS implicit-GEMM dense conv, channels-last.
// Block = 256 threads = G co-groups x S slots (g fastest). Per tap:
//   stage shifted A-tile (VT x CI, coalesced, XOR-swizzled) + W-tap (CI x CO)
//   into LDS, then each thread computes VX voxels x CO2 channels from LDS.
// ---------------------------------------------------------------------------
template<int ID,int IH,int IW,int OD,int OH,int OW,int CI,int CO,
         int S,int VX,int CO2,
         int KD,int KH,int KW,int SD,int SH,int SW,int PD,int PH,int PW>
__global__ __launch_bounds__(256)
void convg(const float* __restrict__ in, float* __restrict__ out,
           const float* __restrict__ wp) {
  constexpr int G    = 256 / S;
  static_assert(G * CO2 == CO, "co tiling mismatch");
  constexpr int VT   = S * VX;
  constexpr int NVOX = OD*OH*OW;
  __shared__ float a_lds[VT * CI];
  __shared__ float w_lds[CI * CO];

  const int g   = threadIdx.x % G;
  const int s   = threadIdx.x / G;
  const int co0 = g * CO2;
  const int vbase = blockIdx.x * VT;

  float acc[VX][CO2];
  #pragma unroll
  for (int u = 0; u < VX; u++)
    #pragma unroll
    for (int cc = 0; cc < CO2; cc++) acc[u][cc] = 0.f;

  constexpr int CI4N = CI / 4;
  constexpr int VST  = 256 / CI4N;
  const int sv  = threadIdx.x / CI4N;
  const int sc4 = threadIdx.x % CI4N;

  #pragma unroll 1
  for (int kz = 0; kz < KD; kz++) {
    #pragma unroll 1
    for (int ky = 0; ky < KH; ky++) {
      #pragma unroll 1
      for (int kx = 0; kx < KW; kx++) {
        __syncthreads();
        const float* wt = wp + (size_t)((kz*KH + ky)*KW + kx) * CI * CO;
        #pragma unroll
        for (int i = 0; i < CI*CO/4/256; i++) {
          int idx = threadIdx.x + i*256;
          *reinterpret_cast<float4*>(&w_lds[idx*4]) =
              *reinterpret_cast<const float4*>(wt + idx*4);
        }
        #pragma unroll
        for (int rsub = 0; rsub < VT/VST; rsub++) {
          int vox = rsub*VST + sv;
          int gv  = vbase + vox;
          int vc  = gv < NVOX ? gv : 0;
          int ox = vc % OW; int tt = vc / OW; int oy = tt % OH; int oz = tt / OH;
          int iz = oz*SD - PD + kz;
          int iy = oy*SH - PH + ky;
          int ix = ox*SW - PW + kx;
          bool ok = (gv < NVOX) & ((unsigned)iz < (unsigned)ID)
                  & ((unsigned)iy < (unsigned)IH) & ((unsigned)ix < (unsigned)IW);
          float4 v = make_float4(0.f,0.f,0.f,0.f);
          if (ok) {
            int ipos = (iz*IH + iy)*IW + ix;
            v = *reinterpret_cast<const float4*>(in + (size_t)ipos*CI + sc4*4);
          }
          int dw = vox*CI + ((sc4*4) ^ ((vox & 7) << 2));
          *reinterpret_cast<float4*>(&a_lds[dw]) = v;
        }
        __syncthreads();
        #pragma unroll
        for (int c4 = 0; c4 < CI/4; c4++) {
          float wr[4][CO2];
          #pragma unroll
          for (int jj = 0; jj < 4; jj++)
            #pragma unroll
            for (int q = 0; q < CO2/4; q++) {
              float4 wv = *reinterpret_cast<const float4*>(
                  &w_lds[(c4*4 + jj)*CO + co0 + q*4]);
              wr[jj][q*4+0] = wv.x; wr[jj][q*4+1] = wv.y;
              wr[jj][q*4+2] = wv.z; wr[jj][q*4+3] = wv.w;
            }
          #pragma unroll
          for (int u = 0; u < VX; u++) {
            int r = s + S*u;
            float4 a4 = *reinterpret_cast<const float4*>(
                &a_lds[r*CI + ((c4*4) ^ ((r & 7) << 2))]);
            float av[4] = {a4.x, a4.y, a4.z, a4.w};
            #pragma unroll
            for (int jj = 0; jj < 4; jj++)
              #pragma unroll
              for (int cc = 0; cc < CO2; cc++)
                acc[u][cc] += av[jj] * wr[jj][cc];
          }
        }
      }
    }
  }
  #pragma unroll
  for (int u = 0; u < VX; u++) {
    int gv = vbase + s + S*u;
    if (gv >= NVOX) continue;
    float* o = out + (size_t)gv*CO + co0;
    #pragma unroll
    for (int q = 0; q < CO2/4; q++) {
      float4 v = make_float4(acc[u][q*4+0], acc[u][q*4+1],
                             acc[u][q*4+2], acc[u][q*4+3]);
      *reinterpret_cast<float4*>(o + q*4) = v;
    }
  }
}

// ---------------------------------------------------------------------------
// Tail dense conv 64->64: ONE BLOCK PER OUTPUT VOXEL.
// 256 threads = 64 co-lanes x 4 ci-quarters. Per 4-tap group: stage the 4
// activation rows into LDS (1 coalesced load/thread), FMA from float4 weight
// loads (wq layout [tap][co][ci]), then LDS-reduce the 4 quarters.
// ---------------------------------------------------------------------------
template<int ID,int IH,int IW,int OD,int OH,int OW,
         int KD,int KH,int KW,int SD,int SH,int SW,int PD,int PH,int PW>
__global__ __launch_bounds__(256)
void convt(const float* __restrict__ in, float* __restrict__ out,
           const float* __restrict__ wq) {
  constexpr int NT = KD*KH*KW;
  constexpr int NG = (NT + 3) / 4;
  const int v    = blockIdx.x;
  const int lane = threadIdx.x & 63;   // co (and staging channel)
  const int q    = threadIdx.x >> 6;   // ci quarter / tap-within-group
  int ox = v % OW; int t = v / OW; int oy = t % OH; int oz = t / OH;

  __shared__ float a_lds[4][64];
  __shared__ float red[4][64];
  float acc = 0.f;

  #pragma unroll 1
  for (int tg = 0; tg < NG; tg++) {
    int tap = tg*4 + q;
    float val = 0.f;
    if (tap < NT) {
      int kz = tap / (KH*KW); int rr = tap % (KH*KW);
      int ky = rr / KW;       int kx = rr % KW;
      int iz = oz*SD - PD + kz, iy = oy*SH - PH + ky, ix = ox*SW - PW + kx;
      if ((unsigned)iz < (unsigned)ID && (unsigned)iy < (unsigned)IH &&
          (unsigned)ix < (unsigned)IW)
        val = in[(size_t)((iz*IH + iy)*IW + ix)*64 + lane];
    }
    __syncthreads();
    a_lds[q][lane] = val;
    __syncthreads();
    #pragma unroll
    for (int t4 = 0; t4 < 4; t4++) {
      int tap2 = tg*4 + t4;
      if (tap2 >= NT) break;
      const float* wrow = wq + ((size_t)tap2*64 + lane)*64 + q*16;
      #pragma unroll
      for (int c4 = 0; c4 < 4; c4++) {
        float4 w4 = *reinterpret_cast<const float4*>(wrow + c4*4);
        acc += w4.x * a_lds[t4][q*16 + c4*4 + 0];
        acc += w4.y * a_lds[t4][q*16 + c4*4 + 1];
        acc += w4.z * a_lds[t4][q*16 + c4*4 + 2];
        acc += w4.w * a_lds[t4][q*16 + c4*4 + 3];
      }
    }
  }
  red[q][lane] = acc;
  __syncthreads();
  if (q == 0) {
    float s = red[0][lane] + red[1][lane] + red[2][lane] + red[3][lane];
    out[(size_t)v*64 + lane] = s;
  }
}

// ---------------------------------------------------------------------------
// Downsample mask: mout[v] = OR over taps of in-bounds min_.
// ---------------------------------------------------------------------------
template<int ID,int IH,int IW,int OD,int OH,int OW,int KD,int KH,int KW,
         int SD,int SH,int SW,int PD,int PH,int PW>
__global__ __launch_bounds__(256)
void mask_down(const unsigned char* __restrict__ min_, unsigned char* __restrict__ mout) {
  int v = blockIdx.x * blockDim.x + threadIdx.x;
  if (v >= OD*OH*OW) return;
  int ox = v % OW; int t = v / OW; int oy = t % OH; int oz = t / OH;
  bool any = false;
  for (int kz = 0; kz < KD; kz++) {
    int iz = oz*SD - PD + kz; if ((unsigned)iz >= (unsigned)ID) continue;
    for (int ky = 0; ky < KH; ky++) {
      int iy = oy*SH - PH + ky; if ((unsigned)iy >= (unsigned)IH) continue;
      for (int kx = 0; kx < KW; kx++) {
        int ix = ox*SW - PW + kx; if ((unsigned)ix >= (unsigned)IW) continue;
        any = any || (min_[(iz*IH + iy)*IW + ix] != 0);
      }
    }
  }
  mout[v] = any ? 1 : 0;
}

// ---------------------------------------------------------------------------
// Masked BN stats: per-channel sum, sumsq, count.
// ---------------------------------------------------------------------------
template<int CO, int YD>
__global__ void bn_stats(const float* __restrict__ x, const unsigned char* __restrict__ m,
                         float* __restrict__ stats, int nvox) {
  int c  = threadIdx.x;
  int ty = threadIdx.y;
  float s = 0.f, q = 0.f, cnt = 0.f;
  for (int vox = blockIdx.x*YD + ty; vox < nvox; vox += gridDim.x*YD) {
    bool act = m ? (m[vox] != 0) : true;
    if (act) {
      float v = x[(size_t)vox*CO + c];
      s += v; q += v*v; cnt += 1.f;
    }
  }
  __shared__ float ls[YD][CO];
  __shared__ float lq[YD][CO];
  __shared__ float lc[YD];
  ls[ty][c] = s; lq[ty][c] = q;
  if (c == 0) lc[ty] = cnt;
  __syncthreads();
  if (ty == 0) {
    #pragma unroll
    for (int i = 1; i < YD; i++) { s += ls[i][c]; q += lq[i][c]; }
    atomicAdd(&stats[c], s);
    atomicAdd(&stats[CO + c], q);
    if (c == 0) {
      float tc = 0.f;
      #pragma unroll
      for (int i = 0; i < YD; i++) tc += lc[i];
      atomicAdd(&stats[2*CO], tc);
    }
  }
}

// ---------------------------------------------------------------------------
template<int CO>
__global__ __launch_bounds__(256)
void bn_apply(float* __restrict__ x, const unsigned char* __restrict__ m,
              const float* __restrict__ stats, const float* __restrict__ g,
              const float* __restrict__ b, int nvox) {
  int idx = blockIdx.x * blockDim.x + threadIdx.x;
  int vox = idx / CO, c = idx % CO;
  if (vox >= nvox) return;
  float cnt   = fmaxf(stats[2*CO], 1.f);
  float mean  = stats[c] / cnt;
  float var   = stats[CO + c] / cnt - mean*mean;
  float scale = g[c] * rsqrtf(var + EPSV);
  float v = (x[idx] - mean) * scale + b[c];
  v = fmaxf(v, 0.f);
  bool act = m ? (m[vox] != 0) : true;
  x[idx] = act ? v : 0.f;
}

// ---------------------------------------------------------------------------
__global__ __launch_bounds__(256)
void write_out(const float* __restrict__ x, float* __restrict__ out) {
  int idx = blockIdx.x * blockDim.x + threadIdx.x;
  if (idx >= 64*11*5*25) return;
  int y = idx % 25; int t = idx / 25;
  int z = t % 5;  t /= 5;
  int wx = t % 11; int c = t / 11;
  out[idx] = x[(((z*25 + y)*11) + wx)*64 + c];
}

// ---------------------------------------------------------------------------
extern "C" void kernel_launch(void* const* d_in, const int* in_sizes, int n_in,
                              void* d_out, int out_size, void* d_ws, size_t ws_size,
                              hipStream_t stream) {
  const float* vf    = (const float*)d_in[0];
  const int*   coors = (const int*)d_in[1];
  int n = in_sizes[0] / 16;

  // dict order is INTERLEAVED: vf, coors, bs, shape, (w0,g0,b0), (w1,g1,b1), ...
  const float *w[9], *g[9], *b[9];
  for (int i = 0; i < 9; i++) {
    w[i] = (const float*)d_in[4 + 3*i];
    g[i] = (const float*)d_in[5 + 3*i];
    b[i] = (const float*)d_in[6 + 3*i];
  }
  float* out = (float*)d_out;

  char* wsb = (char*)d_ws;
  size_t off = 0;
  auto alloc = [&](size_t bytes) -> void* {
    void* p = wsb + off;
    off += (bytes + 255) & ~(size_t)255;
    return p;
  };
  int*   grid0 = (int*)  alloc((size_t)40*200*200*4);
  float* wp    = (float*)alloc((size_t)454656*4);
  float* wq    = (float*)alloc((size_t)233472*4);
  float* fA    = (float*)alloc((size_t)n*16*4);
  float* fB    = (float*)alloc((size_t)n*16*4);
  float* dA    = (float*)alloc((size_t)20*100*100*32*4);
  float* dB    = (float*)alloc((size_t)20*100*100*32*4);
  unsigned char* m2 = (unsigned char*)alloc(20*100*100);
  unsigned char* m4 = (unsigned char*)alloc(10*50*50);
  unsigned char* m6 = (unsigned char*)alloc(5*25*24);
  unsigned char* m8 = (unsigned char*)alloc(5*25*11);
  float* stats = (float*)alloc((size_t)9*160*4);

  float* st[9];
  for (int i = 0; i < 9; i++) st[i] = stats + i*160;

  hipMemsetAsync(grid0, 0xFF, (size_t)40*200*200*4, stream);
  hipMemsetAsync(stats, 0, (size_t)9*160*4, stream);

  WPtrs wps; for (int i = 0; i < 9; i++) wps.w[i] = w[i];
  repack_w<<<idiv(454656,256), 256, 0, stream>>>(wps, wp);
  repack_wq<<<idiv(233472,256), 256, 0, stream>>>(w[6], w[7], w[8], wq);
  scatter_grid<<<idiv(n,256), 256, 0, stream>>>(coors, grid0, n);

  const int WO0=0, WO1=6912, WO2=13824, WO3=27648, WO4=55296,
            WO5=110592;
  const int WQ6=0, WQ7=110592, WQ8=221184;

  // ---- L0, L1: sparse subm 16->16 ----
  subm16<<<idiv(n,256), 256, 0, stream>>>(vf, fA, coors, grid0, wp + WO0, n);
  bn_stats<16,16><<<imin(256, idiv(n,16)), dim3(16,16), 0, stream>>>(fA, nullptr, st[0], n);
  bn_apply<16><<<idiv(n*16,256), 256, 0, stream>>>(fA, nullptr, st[0], g[0], b[0], n);

  subm16<<<idiv(n,256), 256, 0, stream>>>(fA, fB, coors, grid0, wp + WO1, n);
  bn_stats<16,16><<<imin(256, idiv(n,16)), dim3(16,16), 0, stream>>>(fB, nullptr, st[1], n);
  bn_apply<16><<<idiv(n*16,256), 256, 0, stream>>>(fB, nullptr, st[1], g[1], b[1], n);

  // ---- L2: down 16->32 -> dense (20,100,100), COPT=16 x 2 groups ----
  down16to32<<<dim3(idiv(200000,256),2), 256, 0, stream>>>(fB, grid0, dA, m2, wp + WO2);
  bn_stats<32,8><<<imin(256, idiv(200000,8)), dim3(32,8), 0, stream>>>(dA, m2, st[2], 200000);
  bn_apply<32><<<idiv(200000*32,256), 256, 0, stream>>>(dA, m2, st[2], g[2], b[2], 200000);

  // ---- L3: subm 32->32 dense, LDS implicit-GEMM (VT=256) ----
  convg<20,100,100, 20,100,100, 32,32, 32,8,4, 3,3,3, 1,1,1, 1,1,1>
      <<<idiv(200000,256), 256, 0, stream>>>(dA, dB, wp + WO3);
  bn_stats<32,8><<<imin(256, idiv(200000,8)), dim3(32,8), 0, stream>>>(dB, m2, st[3], 200000);
  bn_apply<32><<<idiv(200000*32,256), 256, 0, stream>>>(dB, m2, st[3], g[3], b[3], 200000);

  // ---- L4: down 32->64 -> (10,50,50), VT=64 (S=16,VX=4,CO2=4) + mask ----
  convg<20,100,100, 10,50,50, 32,64, 16,4,4, 3,3,3, 2,2,2, 1,1,1>
      <<<idiv(25000,64), 256, 0, stream>>>(dB, dA, wp + WO4);
  mask_down<20,100,100, 10,50,50, 3,3,3, 2,2,2, 1,1,1>
      <<<idiv(25000,256), 256, 0, stream>>>(m2, m4);
  bn_stats<64,4><<<imin(256, idiv(25000,4)), dim3(64,4), 0, stream>>>(dA, m4, st[4], 25000);
  bn_apply<64><<<idiv(25000*64,256), 256, 0, stream>>>(dA, m4, st[4], g[4], b[4], 25000);

  // ---- L5: subm 64->64, VT=64 (S=16,VX=4,CO2=4) ----
  convg<10,50,50, 10,50,50, 64,64, 16,4,4, 3,3,3, 1,1,1, 1,1,1>
      <<<idiv(25000,64), 256, 0, stream>>>(dA, dB, wp + WO5);
  bn_stats<64,4><<<imin(256, idiv(25000,4)), dim3(64,4), 0, stream>>>(dB, m4, st[5], 25000);
  bn_apply<64><<<idiv(25000*64,256), 256, 0, stream>>>(dB, m4, st[5], g[5], b[5], 25000);

  // ---- L6: down 64->64 s(2,2,2) p(1,1,0) -> (5,25,24), block-per-voxel ----
  convt<10,50,50, 5,25,24, 3,3,3, 2,2,2, 1,1,0>
      <<<3000, 256, 0, stream>>>(dB, dA, wq + WQ6);
  mask_down<10,50,50, 5,25,24, 3,3,3, 2,2,2, 1,1,0>
      <<<idiv(3000,256), 256, 0, stream>>>(m4, m6);
  bn_stats<64,4><<<imin(256, idiv(3000,4)), dim3(64,4), 0, stream>>>(dA, m6, st[6], 3000);
  bn_apply<64><<<idiv(3000*64,256), 256, 0, stream>>>(dA, m6, st[6], g[6], b[6], 3000);

  // ---- L7: subm 64->64, block-per-voxel ----
  convt<5,25,24, 5,25,24, 3,3,3, 1,1,1, 1,1,1>
      <<<3000, 256, 0, stream>>>(dA, dB, wq + WQ7);
  bn_stats<64,4><<<imin(256, idiv(3000,4)), dim3(64,4), 0, stream>>>(dB, m6, st[7], 3000);
  bn_apply<64><<<idiv(3000*64,256), 256, 0, stream>>>(dB, m6, st[7], g[7], b[7], 3000);

  // ---- L8: down 64->64 k(1,1,3) s(1,1,2) -> (5,25,11), block-per-voxel ----
  convt<5,25,24, 5,25,11, 1,1,3, 1,1,2, 0,0,0>
      <<<1375, 256, 0, stream>>>(dB, dA, wq + WQ8);
  mask_down<5,25,24, 5,25,11, 1,1,3, 1,1,2, 0,0,0>
      <<<idiv(1375,256), 256, 0, stream>>>(m6, m8);
  bn_stats<64,4><<<imin(256, idiv(1375,4)), dim3(64,4), 0, stream>>>(dA, m8, st[8], 1375);
  bn_apply<64><<<idiv(1375*64,256), 256, 0, stream>>>(dA, m8, st[8], g[8], b[8], 1375);

  write_out<<<idiv(88000,256), 256, 0, stream>>>(dA, out);
}